// Round 3
// baseline (1139.106 us; speedup 1.0000x reference)
//
#include <hip/hip_runtime.h>

// ---------------------------------------------------------------------------
// TTT base module: out = (scan(XC,XB,XA,coeff) ) @ Wo^T
// Scan v3: all matmuls are 16x16x16bf16_1k MFMAs. W1 state lives in 16
// C-layout f32 accumulators; C-layout == B-frag layout for K=16, so the
// per-iteration W1 transform is a pure in-register bf16 pack (no LDS).
// xc/xb staged raw bf16 (A-frags via ds_read_b64, exact). b1 in registers.
// ---------------------------------------------------------------------------

typedef __attribute__((ext_vector_type(4))) float float4v;
typedef __attribute__((ext_vector_type(4))) short short4v;
typedef __attribute__((ext_vector_type(2))) unsigned int uint2v;
typedef __attribute__((ext_vector_type(4))) unsigned int uint4v;
typedef __attribute__((ext_vector_type(8))) __bf16 bf16x8;

__device__ __forceinline__ unsigned short f2bf(float f) {
  unsigned int u = __builtin_bit_cast(unsigned int, f);
  u += 0x7FFFu + ((u >> 16) & 1u);
  return (unsigned short)(u >> 16);
}
__device__ __forceinline__ float bf2f(unsigned short s) {
  unsigned int u = ((unsigned int)s) << 16;
  return __builtin_bit_cast(float, u);
}
// pack two f32 -> two bf16 (round-half-up) in one v_perm
__device__ __forceinline__ unsigned int pkbf(float a, float b) {
  const unsigned int ua = __builtin_bit_cast(unsigned int, a) + 0x8000u;
  const unsigned int ub = __builtin_bit_cast(unsigned int, b) + 0x8000u;
  return __builtin_amdgcn_perm(ub, ua, 0x07060302u);
}
__device__ __forceinline__ short4v pkbf4(float4v v) {
  uint2v u;
  u[0] = pkbf(v[0], v[1]);
  u[1] = pkbf(v[2], v[3]);
  return __builtin_bit_cast(short4v, u);
}
__device__ __forceinline__ void lds_load16(const void* g, void* l) {
  __builtin_amdgcn_global_load_lds((const __attribute__((address_space(1))) void*)g,
                                   (__attribute__((address_space(3))) void*)l, 16, 0, 0);
}

__device__ __forceinline__ void store_out(float* p, float v) { *p = v; }
__device__ __forceinline__ void store_out(unsigned short* p, float v) { *p = f2bf(v); }

// ---------------------------------------------------------------------------
// C[m,n] = sum_k A[m,k] * B[n,k]   (bf16, B^T GEMM, 128x128 tile, BK=32)
// ---------------------------------------------------------------------------
template <typename OUT>
__global__ __launch_bounds__(256) void gemm_bt(
    const unsigned short* __restrict__ A, const unsigned short* __restrict__ B,
    OUT* __restrict__ C, int M, int N, int K) {
  __shared__ unsigned short sA[128 * 32];
  __shared__ unsigned short sB[128 * 32];
  const int tid = threadIdx.x;
  const int wave = tid >> 6;
  const int lane = tid & 63;
  const int quad = lane >> 4;
  const int l15 = lane & 15;
  const int wm = (wave >> 1) * 64;
  const int wn = (wave & 1) * 64;
  const int bm = blockIdx.y * 128;
  const int bn = blockIdx.x * 128;

  float4v acc[4][4];
#pragma unroll
  for (int i = 0; i < 4; ++i)
#pragma unroll
    for (int j = 0; j < 4; ++j) acc[i][j] = (float4v){0.f, 0.f, 0.f, 0.f};

  const int srow = tid >> 2;
  const int scol = (tid & 3) * 8;
  const unsigned short* aptr = A + (size_t)(bm + srow) * K + scol;
  const unsigned short* bptr = B + (size_t)(bn + srow) * K + scol;
  unsigned short* sAw0 = &sA[wave * 512];
  unsigned short* sAw1 = &sA[2048 + wave * 512];
  unsigned short* sBw0 = &sB[wave * 512];
  unsigned short* sBw1 = &sB[2048 + wave * 512];
  const size_t astep = (size_t)64 * K;

  for (int kt = 0; kt < K; kt += 32) {
    __syncthreads();
    lds_load16(aptr + kt, sAw0);
    lds_load16(aptr + kt + astep, sAw1);
    lds_load16(bptr + kt, sBw0);
    lds_load16(bptr + kt + astep, sBw1);
    __syncthreads();
    bf16x8 af[4], bf[4];
#pragma unroll
    for (int i = 0; i < 4; ++i)
      af[i] = *(const bf16x8*)&sA[(wm + i * 16 + l15) * 32 + quad * 8];
#pragma unroll
    for (int j = 0; j < 4; ++j)
      bf[j] = *(const bf16x8*)&sB[(wn + j * 16 + l15) * 32 + quad * 8];
#pragma unroll
    for (int i = 0; i < 4; ++i)
#pragma unroll
      for (int j = 0; j < 4; ++j)
        acc[i][j] = __builtin_amdgcn_mfma_f32_16x16x32_bf16(af[i], bf[j], acc[i][j], 0, 0, 0);
  }

#pragma unroll
  for (int i = 0; i < 4; ++i) {
    const int row0 = bm + wm + i * 16 + quad * 4;
#pragma unroll
    for (int j = 0; j < 4; ++j) {
      const int col = bn + wn + j * 16 + l15;
#pragma unroll
      for (int r = 0; r < 4; ++r)
        store_out(&C[(size_t)(row0 + r) * N + col], acc[i][j][r]);
    }
  }
}

// ---------------------------------------------------------------------------
__global__ __launch_bounds__(256) void f32_to_bf16_k(const float* __restrict__ s,
                                                     unsigned short* __restrict__ d, int n) {
  const int i = (blockIdx.x * 256 + threadIdx.x) * 8;
  if (i >= n) return;
  const float4v a = *(const float4v*)(s + i);
  const float4v b = *(const float4v*)(s + i + 4);
  uint4v o;
  o[0] = (unsigned int)f2bf(a[0]) | ((unsigned int)f2bf(a[1]) << 16);
  o[1] = (unsigned int)f2bf(a[2]) | ((unsigned int)f2bf(a[3]) << 16);
  o[2] = (unsigned int)f2bf(b[0]) | ((unsigned int)f2bf(b[1]) << 16);
  o[3] = (unsigned int)f2bf(b[2]) | ((unsigned int)f2bf(b[3]) << 16);
  *(uint4v*)(d + i) = o;
}

// ---------------------------------------------------------------------------
__global__ __launch_bounds__(256) void coeff_k(const unsigned short* __restrict__ ilr,
                                               const float* __restrict__ lb,
                                               float* __restrict__ coeff) {
  const int gid = blockIdx.x * 256 + threadIdx.x;
  const int row = gid >> 5;
  const int h = gid & 31;
  const float v = bf2f(ilr[row * 128 + h]) + lb[h];
  const float sig = 1.0f / (1.0f + __expf(-v));
  const int b = row >> 11;
  const int pos = row & 2047;
  const int cc = pos >> 4;
  const int k = pos & 15;
  coeff[((((size_t)b * 32 + h) * 128 + cc) << 4) + k] = sig / (64.0f * (float)(k + 1));
}

// ---------------------------------------------------------------------------
// TTT scan v3: one block = one (b,h); 1 wave; 128 sequential chunks of K=16.
// ---------------------------------------------------------------------------
__global__ __launch_bounds__(64, 1) void ttt_scan(
    const unsigned short* __restrict__ XC, const unsigned short* __restrict__ XB,
    const unsigned short* __restrict__ XA, const float* __restrict__ coeff,
    const float* __restrict__ lnw, const float* __restrict__ lnb,
    const float* __restrict__ W1i, const float* __restrict__ b1i,
    unsigned short* __restrict__ XCW) {
  const int b = blockIdx.x >> 5;
  const int h = blockIdx.x & 31;
  const int lane = threadIdx.x;
  const int quad = lane >> 4;
  const int l15 = lane & 15;

  __shared__ unsigned short sXCr[16 * 64];  // raw bf16 [t][f]
  __shared__ unsigned short sXBr[16 * 64];
  __shared__ float sTs[16 * 68];            // (xa-xb) f32 [t][f], padded
  __shared__ float sAttn[16 * 20];

  float gam[4], bet[4], b1v[4];
#pragma unroll
  for (int nt = 0; nt < 4; ++nt) {
    gam[nt] = lnw[h * 64 + nt * 16 + l15];
    bet[nt] = lnb[h * 64 + nt * 16 + l15];
    b1v[nt] = b1i[h * 64 + nt * 16 + l15];
  }
  // W1 state, C-layout per tile (mt,nt): elem (f=16mt+quad*4+r, g=16nt+l15)
  float4v W1r[16];
  short4v w1b[16];  // bf16 B-frags (K=16: B[k=quad*4+j][n=l15] == C-layout)
#pragma unroll
  for (int mt = 0; mt < 4; ++mt)
#pragma unroll
    for (int nt = 0; nt < 4; ++nt) {
      float4v v;
#pragma unroll
      for (int r = 0; r < 4; ++r)
        v[r] = W1i[(size_t)h * 4096 + (size_t)(mt * 16 + quad * 4 + r) * 64 + nt * 16 + l15];
      W1r[mt * 4 + nt] = v;
      w1b[mt * 4 + nt] = pkbf4(v);
    }

  const int srow = lane >> 2;        // 0..15
  const int scol = (lane & 3) * 16;  // 0,16,32,48
  const size_t hdoff = (size_t)h * 64;
  const size_t browoff = (size_t)b * 2048;
  const size_t cobase = (((size_t)b * 32 + h) * 128) * 16;
  const float inv64 = 1.0f / 64.0f;
  const float4v zero4 = {0.f, 0.f, 0.f, 0.f};

  // ---- prefetch chunk 0 ----
  uint4v pxc0, pxc1, pxb0, pxb1, pxa0, pxa1;
  float pco;
  {
    const size_t goff = (browoff + (size_t)srow) * 2048 + hdoff + scol;
    pxc0 = *(const uint4v*)(XC + goff);
    pxc1 = *(const uint4v*)(XC + goff + 8);
    pxb0 = *(const uint4v*)(XB + goff);
    pxb1 = *(const uint4v*)(XB + goff + 8);
    pxa0 = *(const uint4v*)(XA + goff);
    pxa1 = *(const uint4v*)(XA + goff + 8);
    pco = coeff[cobase + l15];
  }

  for (int c = 0; c < 128; ++c) {
    const uint4v xc0 = pxc0, xc1 = pxc1, xb0 = pxb0, xb1 = pxb1, xa0 = pxa0, xa1 = pxa1;
    const float co = pco;
    {
      const int cn = (c < 127) ? c + 1 : 127;
      const size_t goff = (browoff + (size_t)(cn * 16 + srow)) * 2048 + hdoff + scol;
      pxc0 = *(const uint4v*)(XC + goff);
      pxc1 = *(const uint4v*)(XC + goff + 8);
      pxb0 = *(const uint4v*)(XB + goff);
      pxb1 = *(const uint4v*)(XB + goff + 8);
      pxa0 = *(const uint4v*)(XA + goff);
      pxa1 = *(const uint4v*)(XA + goff + 8);
      pco = coeff[cobase + (size_t)cn * 16 + l15];
    }

    // ---- stage: raw bf16 xc/xb; f32 (xa-xb) targets ----
    *(uint4v*)&sXCr[srow * 64 + scol] = xc0;
    *(uint4v*)&sXCr[srow * 64 + scol + 8] = xc1;
    *(uint4v*)&sXBr[srow * 64 + scol] = xb0;
    *(uint4v*)&sXBr[srow * 64 + scol + 8] = xb1;
    {
      float tv[16];
#pragma unroll
      for (int t2 = 0; t2 < 4; ++t2) {
        const float blo = __builtin_bit_cast(float, xb0[t2] << 16);
        const float bhi = __builtin_bit_cast(float, xb0[t2] & 0xFFFF0000u);
        const float alo = __builtin_bit_cast(float, xa0[t2] << 16);
        const float ahi = __builtin_bit_cast(float, xa0[t2] & 0xFFFF0000u);
        tv[t2 * 2] = alo - blo;
        tv[t2 * 2 + 1] = ahi - bhi;
        const float blo1 = __builtin_bit_cast(float, xb1[t2] << 16);
        const float bhi1 = __builtin_bit_cast(float, xb1[t2] & 0xFFFF0000u);
        const float alo1 = __builtin_bit_cast(float, xa1[t2] << 16);
        const float ahi1 = __builtin_bit_cast(float, xa1[t2] & 0xFFFF0000u);
        tv[8 + t2 * 2] = alo1 - blo1;
        tv[8 + t2 * 2 + 1] = ahi1 - bhi1;
      }
#pragma unroll
      for (int k4 = 0; k4 < 4; ++k4)
        *(float4v*)&sTs[srow * 68 + scol + k4 * 4] =
            (float4v){tv[k4 * 4], tv[k4 * 4 + 1], tv[k4 * 4 + 2], tv[k4 * 4 + 3]};
    }

    // ---- A-frags (exact, raw bf16): A[m=l15][k=quad*4+j], chunk mt ----
    short4v xbA[4], xcA[4];
#pragma unroll
    for (int mt = 0; mt < 4; ++mt) {
      xbA[mt] = *(const short4v*)&sXBr[l15 * 64 + mt * 16 + quad * 4];
      xcA[mt] = *(const short4v*)&sXCr[l15 * 64 + mt * 16 + quad * 4];
    }
    float cof[4];
#pragma unroll
    for (int r = 0; r < 4; ++r) cof[r] = __shfl(co, quad * 4 + r);

    // ---- caf (W1-update A-frag, off-chain): A[f=mt*16+l15][k=t=quad*4+jj] ----
    short4v caf[4];
#pragma unroll
    for (int mt = 0; mt < 4; ++mt) {
      float4v cv;
#pragma unroll
      for (int jj = 0; jj < 4; ++jj) {
        const unsigned int raw = sXBr[(quad * 4 + jj) * 64 + mt * 16 + l15];
        cv[jj] = -cof[jj] * __builtin_bit_cast(float, raw << 16);
      }
      caf[mt] = pkbf4(cv);
    }

    // ---- Attn = xc@xb^T (B-frag of xb^T == A-frag regs of xb) ----
    float4v at = __builtin_amdgcn_mfma_f32_16x16x16bf16_1k(xcA[0], xbA[0], zero4, 0, 0, 0);
    at = __builtin_amdgcn_mfma_f32_16x16x16bf16_1k(xcA[1], xbA[1], at, 0, 0, 0);
    at = __builtin_amdgcn_mfma_f32_16x16x16bf16_1k(xcA[2], xbA[2], at, 0, 0, 0);
    at = __builtin_amdgcn_mfma_f32_16x16x16bf16_1k(xcA[3], xbA[3], at, 0, 0, 0);
#pragma unroll
    for (int r = 0; r < 4; ++r) sAttn[(quad * 4 + r) * 20 + l15] = at[r];

    // ---- Z1 = xb@W1 + b1 (C-layout) ----
    float4v z[4];
#pragma unroll
    for (int nt = 0; nt < 4; ++nt) {
      float4v t = __builtin_amdgcn_mfma_f32_16x16x16bf16_1k(xbA[0], w1b[nt], zero4, 0, 0, 0);
      t = __builtin_amdgcn_mfma_f32_16x16x16bf16_1k(xbA[1], w1b[4 + nt], t, 0, 0, 0);
      t = __builtin_amdgcn_mfma_f32_16x16x16bf16_1k(xbA[2], w1b[8 + nt], t, 0, 0, 0);
      t = __builtin_amdgcn_mfma_f32_16x16x16bf16_1k(xbA[3], w1b[12 + nt], t, 0, 0, 0);
#pragma unroll
      for (int r = 0; r < 4; ++r) t[r] += b1v[nt];
      z[nt] = t;
    }
    // xc@W1 part of Z1_bar (independent of grad -> issue early)
    float4v zb[4];
#pragma unroll
    for (int nt = 0; nt < 4; ++nt) {
      float4v t = __builtin_amdgcn_mfma_f32_16x16x16bf16_1k(xcA[0], w1b[nt], zero4, 0, 0, 0);
      t = __builtin_amdgcn_mfma_f32_16x16x16bf16_1k(xcA[1], w1b[4 + nt], t, 0, 0, 0);
      t = __builtin_amdgcn_mfma_f32_16x16x16bf16_1k(xcA[2], w1b[8 + nt], t, 0, 0, 0);
      t = __builtin_amdgcn_mfma_f32_16x16x16bf16_1k(xcA[3], w1b[12 + nt], t, 0, 0, 0);
      zb[nt] = t;
    }

    // ---- LN fused L2 backward -> grad ----
    float s1[4], s2[4];
#pragma unroll
    for (int r = 0; r < 4; ++r) {
      s1[r] = z[0][r] + z[1][r] + z[2][r] + z[3][r];
      s2[r] = z[0][r] * z[0][r] + z[1][r] * z[1][r] + z[2][r] * z[2][r] + z[3][r] * z[3][r];
    }
#pragma unroll
    for (int m = 1; m <= 8; m <<= 1)
#pragma unroll
      for (int r = 0; r < 4; ++r) {
        s1[r] += __shfl_xor(s1[r], m);
        s2[r] += __shfl_xor(s2[r], m);
      }
    float mu[4], rstd[4];
#pragma unroll
    for (int r = 0; r < 4; ++r) {
      mu[r] = s1[r] * inv64;
      const float var = s2[r] * inv64 - mu[r] * mu[r];
      rstd[r] = rsqrtf(var + 1e-6f);
    }
    float xh[4][4], gg[4][4];
#pragma unroll
    for (int nt = 0; nt < 4; ++nt)
#pragma unroll
      for (int r = 0; r < 4; ++r) {
        const float xhat = (z[nt][r] - mu[r]) * rstd[r];
        xh[nt][r] = xhat;
        const float y = gam[nt] * xhat + bet[nt];
        const float tgt = sTs[(quad * 4 + r) * 68 + nt * 16 + l15];
        gg[nt][r] = (y - tgt) * gam[nt];
      }
    float sg[4], sgx[4];
#pragma unroll
    for (int r = 0; r < 4; ++r) {
      sg[r] = gg[0][r] + gg[1][r] + gg[2][r] + gg[3][r];
      sgx[r] = gg[0][r] * xh[0][r] + gg[1][r] * xh[1][r] + gg[2][r] * xh[2][r] + gg[3][r] * xh[3][r];
    }
#pragma unroll
    for (int m = 1; m <= 8; m <<= 1)
#pragma unroll
      for (int r = 0; r < 4; ++r) {
        sg[r] += __shfl_xor(sg[r], m);
        sgx[r] += __shfl_xor(sgx[r], m);
      }
    float grad[4][4];
    short4v gradb[4];  // B-frag (== C-layout)
#pragma unroll
    for (int nt = 0; nt < 4; ++nt) {
      float4v gv;
#pragma unroll
      for (int r = 0; r < 4; ++r) {
        gv[r] = (64.0f * gg[nt][r] - sg[r] - xh[nt][r] * sgx[r]) * (rstd[r] * inv64);
        grad[nt][r] = gv[r];
      }
      gradb[nt] = pkbf4(gv);
    }

    // ---- m1f = -((Attn+1) o E), A-frag [m=l15][k=quad*4+jj] ----
    const float4v av = *(const float4v*)&sAttn[l15 * 20 + quad * 4];
    short4v m1f;
    {
      float4v mv;
#pragma unroll
      for (int jj = 0; jj < 4; ++jj) {
        const int k = quad * 4 + jj;
        const float e = (k <= l15) ? cof[jj] : 0.0f;
        mv[jj] = -(av[jj] + 1.0f) * e;
      }
      m1f = pkbf4(mv);
    }

    // ---- Z1_bar = zb - ((Attn+1) o E)@grad + b1 ----
#pragma unroll
    for (int nt = 0; nt < 4; ++nt) {
      float4v t = __builtin_amdgcn_mfma_f32_16x16x16bf16_1k(m1f, gradb[nt], zb[nt], 0, 0, 0);
#pragma unroll
      for (int r = 0; r < 4; ++r) t[r] += b1v[nt];
      z[nt] = t;
    }

    // ---- out = xc + LN(Z1_bar) ----
#pragma unroll
    for (int r = 0; r < 4; ++r) {
      s1[r] = z[0][r] + z[1][r] + z[2][r] + z[3][r];
      s2[r] = z[0][r] * z[0][r] + z[1][r] * z[1][r] + z[2][r] * z[2][r] + z[3][r] * z[3][r];
    }
#pragma unroll
    for (int m = 1; m <= 8; m <<= 1)
#pragma unroll
      for (int r = 0; r < 4; ++r) {
        s1[r] += __shfl_xor(s1[r], m);
        s2[r] += __shfl_xor(s2[r], m);
      }
#pragma unroll
    for (int r = 0; r < 4; ++r) {
      mu[r] = s1[r] * inv64;
      const float var = s2[r] * inv64 - mu[r] * mu[r];
      rstd[r] = rsqrtf(var + 1e-6f);
    }
#pragma unroll
    for (int nt = 0; nt < 4; ++nt)
#pragma unroll
      for (int r = 0; r < 4; ++r) {
        const float xhat = (z[nt][r] - mu[r]) * rstd[r];
        const float y = gam[nt] * xhat + bet[nt];
        const float xcv = bf2f(sXCr[(quad * 4 + r) * 64 + nt * 16 + l15]);
        XCW[(browoff + (size_t)(c * 16 + quad * 4 + r)) * 2048 + hdoff + nt * 16 + l15] =
            f2bf(xcv + y);
      }

    // ---- b1 -= sum_t co_t * grad[t][:]  (registers, full-wave reduce) ----
#pragma unroll
    for (int nt = 0; nt < 4; ++nt) {
      float pb = cof[0] * grad[nt][0] + cof[1] * grad[nt][1] + cof[2] * grad[nt][2] +
                 cof[3] * grad[nt][3];
      pb += __shfl_xor(pb, 16);
      pb += __shfl_xor(pb, 32);
      b1v[nt] -= pb;
    }

    // ---- W1 -= (co o xb)^T @ grad; repack bf16 B-frags for next iter ----
#pragma unroll
    for (int mt = 0; mt < 4; ++mt)
#pragma unroll
      for (int nt = 0; nt < 4; ++nt) {
        W1r[mt * 4 + nt] =
            __builtin_amdgcn_mfma_f32_16x16x16bf16_1k(caf[mt], gradb[nt], W1r[mt * 4 + nt], 0, 0, 0);
        w1b[mt * 4 + nt] = pkbf4(W1r[mt * 4 + nt]);
      }
  }
}

// ---------------------------------------------------------------------------
extern "C" void kernel_launch(void* const* d_in, const int* in_sizes, int n_in,
                              void* d_out, int out_size, void* d_ws, size_t ws_size,
                              hipStream_t stream) {
  const float* hs = (const float*)d_in[0];
  const float* Wq = (const float*)d_in[1];
  const float* Wk = (const float*)d_in[2];
  const float* Wv = (const float*)d_in[3];
  const float* Wo = (const float*)d_in[4];
  const float* lw = (const float*)d_in[5];
  const float* lb = (const float*)d_in[6];
  const float* lnw = (const float*)d_in[7];
  const float* lnb = (const float*)d_in[8];
  const float* W1i = (const float*)d_in[9];
  const float* b1i = (const float*)d_in[10];
  float* out = (float*)d_out;
  char* ws = (char*)d_ws;

  unsigned short* hsb = (unsigned short*)(ws);               // 33554432 (hs bf16; reused as XCW)
  unsigned short* wqb = (unsigned short*)(ws + 33554432);    // 8388608
  unsigned short* wkb = (unsigned short*)(ws + 41943040);    // 8388608
  unsigned short* wvb = (unsigned short*)(ws + 50331648);    // 8388608
  unsigned short* wob = (unsigned short*)(ws + 58720256);    // 8388608
  unsigned short* lwb = (unsigned short*)(ws + 67108864);    // 524288
  unsigned short* XCb = (unsigned short*)(ws + 67633152);    // 33554432
  unsigned short* XBb = (unsigned short*)(ws + 101187584);   // 33554432
  unsigned short* XAb = (unsigned short*)(ws + 134742016);   // 33554432
  unsigned short* ilrb = (unsigned short*)(ws + 168296448);  // 2097152
  float* coeff = (float*)(ws + 170393600);                   // 1048576

  f32_to_bf16_k<<<8192, 256, 0, stream>>>(hs, hsb, 16777216);
  f32_to_bf16_k<<<2048, 256, 0, stream>>>(Wq, wqb, 4194304);
  f32_to_bf16_k<<<2048, 256, 0, stream>>>(Wk, wkb, 4194304);
  f32_to_bf16_k<<<2048, 256, 0, stream>>>(Wv, wvb, 4194304);
  f32_to_bf16_k<<<2048, 256, 0, stream>>>(Wo, wob, 4194304);
  hipMemsetAsync(lwb, 0, 524288, stream);
  f32_to_bf16_k<<<32, 256, 0, stream>>>(lw, lwb, 65536);

  dim3 blk(256);
  dim3 gbig(16, 64);
  gemm_bt<unsigned short><<<gbig, blk, 0, stream>>>(hsb, wqb, XCb, 8192, 2048, 2048);
  gemm_bt<unsigned short><<<gbig, blk, 0, stream>>>(hsb, wkb, XBb, 8192, 2048, 2048);
  gemm_bt<unsigned short><<<gbig, blk, 0, stream>>>(hsb, wvb, XAb, 8192, 2048, 2048);
  gemm_bt<unsigned short><<<dim3(1, 64), blk, 0, stream>>>(hsb, lwb, ilrb, 8192, 128, 2048);
  coeff_k<<<1024, 256, 0, stream>>>(ilrb, lb, coeff);
  ttt_scan<<<128, 64, 0, stream>>>(XCb, XBb, XAb, coeff, lnw, lnb, W1i, b1i, hsb);
  gemm_bt<float><<<gbig, blk, 0, stream>>>(hsb, wob, out, 8192, 2048, 2048);
}